// Round 2
// baseline (13604.604 us; speedup 1.0000x reference)
//
#include <hip/hip_runtime.h>
#include <math.h>

#define T      512
#define NBATCH 512
#define IN_DIM 64
#define H      100
#define HP     104   // padded h rows (float4-aligned)
#define KP     100   // uniform (padded) contraction length, multiple of 4

// tanh(a) = 1 - 2/(exp(2a)+1)  -- overflow-safe at both ends.
__device__ __forceinline__ float fast_tanh(float a) {
    float e = __expf(2.0f * a);
    return 1.0f - 2.0f / (e + 1.0f);
}

// One block per batch element. Threads 0..127: layer-1 neurons (j=tid),
// threads 128..255: layer-2 neurons (j=tid-128), pipelined one timestep
// behind layer 1. SINGLE uniform code path: L1's x-contribution is padded
// from 64 to 100 with zeros so every thread executes the same 200-FMA dot;
// only base pointers differ. Weight columns live in registers (wA/wB,
// unconditional constant-index init -> SROA-promotable).
__global__ __launch_bounds__(256, 2)
void drnn_kernel(const float* __restrict__ x,
                 const float* __restrict__ W1x, const float* __restrict__ W1h,
                 const float* __restrict__ b1,
                 const float* __restrict__ W2x, const float* __restrict__ W2h,
                 const float* __restrict__ b2,
                 const float* __restrict__ Wo,  const float* __restrict__ bo,
                 float* __restrict__ out)
{
    __shared__ __align__(16) float h1buf[2][HP];
    __shared__ __align__(16) float h2buf[2][HP];
    __shared__ __align__(16) float xbuf[2][HP];   // [64..99] stay 0 forever

    const int tid = threadIdx.x;
    const int b   = blockIdx.x;
    const float* __restrict__ xrow = x + (size_t)b * T * IN_DIM;

    // ---- zero-init LDS state ----
    if (tid < HP) {
        h1buf[0][tid] = 0.f; h1buf[1][tid] = 0.f;
        h2buf[0][tid] = 0.f; h2buf[1][tid] = 0.f;
        if (tid >= IN_DIM) { xbuf[0][tid] = 0.f; xbuf[1][tid] = 0.f; }
    }
    if (tid < IN_DIM) xbuf[0][tid] = xrow[tid];   // x(0)

    const bool isL1 = (tid < 128);
    const int  j    = isL1 ? tid : (tid - 128);
    const bool act  = (j < H);
    const int  jc   = act ? j : (H - 1);          // clamp: inactive lanes load col 99

    // ---- per-thread weight columns in registers ----
    const float* __restrict__ WA = isL1 ? W1x : W2x;
    const float* __restrict__ WB = isL1 ? W1h : W2h;
    const int KA = isL1 ? IN_DIM : H;             // valid rows of WA
    const float bj = isL1 ? b1[jc] : b2[jc];

    float wA[KP], wB[KP];
    #pragma unroll
    for (int k = 0; k < KP; ++k) {
        int kk = (k < KA) ? k : 0;                // keep address in-bounds
        float v = WA[kk * H + jc];
        wA[k] = (k < KA) ? v : 0.f;
    }
    #pragma unroll
    for (int k = 0; k < KP; ++k)
        wB[k] = WB[k * H + jc];

    // ---- even/odd-iteration LDS pointers (selected once) ----
    // even iter i: L1 reads xbuf[0],h1buf[1] writes h1buf[0];
    //              L2 reads h1buf[1],h2buf[0] writes h2buf[1]
    // odd  iter:   slots flipped
    const float4* __restrict__ inA_e = (const float4*)(isL1 ? xbuf[0] : h1buf[1]);
    const float4* __restrict__ inB_e = (const float4*)(isL1 ? h1buf[1] : h2buf[0]);
    float*                     wr_e  = isL1 ? &h1buf[0][j] : &h2buf[1][j];
    const float4* __restrict__ inA_o = (const float4*)(isL1 ? xbuf[1] : h1buf[0]);
    const float4* __restrict__ inB_o = (const float4*)(isL1 ? h1buf[0] : h2buf[1]);
    float*                     wr_o  = isL1 ? &h1buf[1][j] : &h2buf[0][j];

    // ---- x register pipeline (wave 0) ----
    float xr0 = 0.f, xr1 = 0.f;
    if (tid < 64) {
        xr0 = xrow[1 * IN_DIM + tid];   // x(1)
        xr1 = xrow[2 * IN_DIM + tid];   // x(2)
    }

    __syncthreads();

    auto dot = [&](const float4* __restrict__ A, const float4* __restrict__ Bv) {
        float a0 = bj, a1 = 0.f, a2 = 0.f, a3 = 0.f;
        #pragma unroll
        for (int c = 0; c < KP / 4; ++c) {
            float4 v = A[c];
            a0 += v.x * wA[4*c+0]; a1 += v.y * wA[4*c+1];
            a2 += v.z * wA[4*c+2]; a3 += v.w * wA[4*c+3];
        }
        #pragma unroll
        for (int c = 0; c < KP / 4; ++c) {
            float4 v = Bv[c];
            a0 += v.x * wB[4*c+0]; a1 += v.y * wB[4*c+1];
            a2 += v.z * wB[4*c+2]; a3 += v.w * wB[4*c+3];
        }
        return fast_tanh((a0 + a1) + (a2 + a3));
    };

    // Iter i: L1 computes h1(i); L2 computes h2(i-1).
    #pragma unroll 1
    for (int i = 0; i < T; i += 2) {
        // ---- even body ----
        {
            float hv = dot(inA_e, inB_e);
            if (act && (isL1 | (i > 0))) *wr_e = hv;   // skip bogus h2(-1) at i==0
            if (tid < 64) {
                xbuf[1][tid] = xr0;                    // x(i+1)
                xr0 = xr1;
                if (i + 3 < T) xr1 = xrow[(size_t)(i + 3) * IN_DIM + tid];
            }
        }
        __syncthreads();
        // ---- odd body (iter i+1) ----
        {
            float hv = dot(inA_o, inB_o);
            if (act) *wr_o = hv;
            if (tid < 64) {
                xbuf[0][tid] = xr0;                    // x(i+2)
                xr0 = xr1;
                if (i + 4 < T) xr1 = xrow[(size_t)(i + 4) * IN_DIM + tid];
            }
        }
        __syncthreads();
    }

    // ---- tail iter i = T (even parity): only L2 computes h2(T-1) ----
    if (!isL1) {
        float hv = dot(inA_e, inB_e);   // h1buf[1]=h1(T-1), h2buf[0]=h2(T-2)
        if (act) *wr_e = hv;            // -> h2buf[1]
    }
    __syncthreads();

    // ---- epilogue: h1(T-1) in h1buf[1], h2(T-1) in h2buf[1] ----
    if (isL1 && act)
        out[NBATCH + (size_t)b * H + j] = h1buf[1][j];
    if (!isL1 && act)
        out[NBATCH + (size_t)NBATCH * H + (size_t)b * H + j] = h2buf[1][j];

    // out[b] = h2_T . Wo + bo  (wave-0 shuffle reduction)
    if (tid < 64) {
        float v = h2buf[1][tid] * Wo[tid];
        if (tid + 64 < H) v += h2buf[1][tid + 64] * Wo[tid + 64];
        #pragma unroll
        for (int off = 32; off >= 1; off >>= 1) v += __shfl_down(v, off);
        if (tid == 0) out[b] = v + bo[0];
    }
}

extern "C" void kernel_launch(void* const* d_in, const int* in_sizes, int n_in,
                              void* d_out, int out_size, void* d_ws, size_t ws_size,
                              hipStream_t stream) {
    const float* x   = (const float*)d_in[0];
    const float* W1x = (const float*)d_in[1];
    const float* W1h = (const float*)d_in[2];
    const float* b1  = (const float*)d_in[3];
    const float* W2x = (const float*)d_in[4];
    const float* W2h = (const float*)d_in[5];
    const float* b2  = (const float*)d_in[6];
    const float* Wo  = (const float*)d_in[7];
    const float* bo  = (const float*)d_in[8];
    float* out = (float*)d_out;

    drnn_kernel<<<NBATCH, 256, 0, stream>>>(x, W1x, W1h, b1, W2x, W2h, b2,
                                            Wo, bo, out);
}